// Round 3
// baseline (2136.221 us; speedup 1.0000x reference)
//
#include <hip/hip_runtime.h>
#include <stdint.h>

// LSTM autoregressive rollout, batch-split persistent blocks.
// B=8192, HORIZON=64, F=64, ORDER=16, K=256, 4K=1024.
// Block = 32 batch rows, 512 threads (8 waves, 2/SIMD). 256 blocks = 1/CU.
// Weights pre-swizzled to bf16 B-fragment order in d_ws (704KB).
// ks 0..1 parked in registers (64 VGPR/wave), ks 2..3 parked in LDS (128KB/CU);
// ks 4..10 (448KB/step) streamed from L2, double-buffered, with CROSS-STEP
// prefetch: next step's first two buffers issued at the end of this GEMM.
// All in-loop barriers are lgkm-only (raw s_barrier) so global prefetches
// (weights, x_{t+1}) stay in flight across phase boundaries.
// K rows layout: 0..63 = x_t, 64..79 = yp (newest first), 80..335 = h, 336..351 pad.

typedef short v8s __attribute__((ext_vector_type(8)));
typedef float v4f __attribute__((ext_vector_type(4)));

#define NKS 11          // 352/32 k-steps
#define NKCOL 1024      // 4K columns
#define PKR 2           // k-steps parked in registers (ks 0..1)
#define PKL 2           // k-steps parked in LDS (ks 2..3)
#define SK0 (PKR + PKL) // first streamed k-step (4)

__device__ __forceinline__ unsigned bf16u(float f) {
  unsigned u = __float_as_uint(f);
  return (u + 0x7FFFu + ((u >> 16) & 1u)) >> 16;   // RNE fp32->bf16
}
__device__ __forceinline__ float sigm(float x) {
  return __builtin_amdgcn_rcpf(1.f + __expf(-x));
}
__device__ __forceinline__ float tanh_(float x) {
  return 1.f - 2.f * __builtin_amdgcn_rcpf(1.f + __expf(2.f * x));
}
// LDS barrier with LDS-only ordering: does NOT drain vmcnt, so global->reg
// prefetches survive across it. All cross-thread data in this kernel is LDS.
__device__ __forceinline__ void bar_lds() {
  __builtin_amdgcn_sched_barrier(0);
  asm volatile("s_waitcnt lgkmcnt(0)" ::: "memory");
  __builtin_amdgcn_s_barrier();
  __builtin_amdgcn_sched_barrier(0);
}
// Swizzled A-LDS address for element (m, k): tiles of 1KB per (mt, ks),
// within tile lane-linear for the MFMA A-fragment read (lane*16B).
__device__ __forceinline__ int a_addr(int m, int k) {
  return (((m >> 4) * NKS + (k >> 5)) << 10)
       + ((((k >> 3) & 3) * 16 + (m & 15)) << 4)
       + ((k & 7) << 1);
}

// ---------------- weight swizzle prep (once per launch) ----------------
// Wsw[(nt*11 + ks)*64 + lane] = 8 bf16: B[k = ks*32 + (lane>>4)*8 + j][n = nt*16 + (lane&15)]
__global__ void prep_w(const float* __restrict__ ker, const float* __restrict__ rec,
                       uint4* __restrict__ wsw) {
  int tid = blockIdx.x * 256 + threadIdx.x;     // 0 .. 45055 (64 nt * 11 ks * 64 lanes)
  int lane = tid & 63;
  int rest = tid >> 6;
  int ks = rest % NKS;
  int nt = rest / NKS;
  int n  = nt * 16 + (lane & 15);
  int k0 = ks * 32 + ((lane >> 4) & 3) * 8;
  unsigned h[8];
  #pragma unroll
  for (int j = 0; j < 8; ++j) {
    int k = k0 + j;
    float v = 0.f;
    if (k < 80)       v = ker[k * NKCOL + n];          // x rows 0..63, yp rows 64..79
    else if (k < 336) v = rec[(k - 80) * NKCOL + n];   // h rows
    h[j] = bf16u(v);
  }
  uint4 o;
  o.x = h[0] | (h[1] << 16); o.y = h[2] | (h[3] << 16);
  o.z = h[4] | (h[5] << 16); o.w = h[6] | (h[7] << 16);
  wsw[tid] = o;
}

// ---------------- main persistent kernel ----------------
__global__ __launch_bounds__(512, 2)
void lstm_main(const float* __restrict__ x, const float* __restrict__ y0,
               const float* __restrict__ bias, const float* __restrict__ dw,
               const float* __restrict__ db, const v8s* __restrict__ wv,
               float* __restrict__ out) {
  __shared__ __align__(16) char a_lds[2 * NKS * 1024];   // 22528 B swizzled A
  __shared__ __align__(16) v8s w_lds[PKL * 64 * 64];     // 131072 B parked W (ks 2..3)
  __shared__ float predbuf[32][8];
  __shared__ float predf[32];

  const int tid  = threadIdx.x;
  const int lane = tid & 63;
  const int wave = tid >> 6;
  const int l15  = lane & 15;
  const int quad = lane >> 4;
  const int b0   = blockIdx.x * 32;

  // zero A (h rows must be 0 at t=0; pad rows stay 0 forever)
  for (int i = tid; i < 2 * NKS * 256; i += 512) ((unsigned*)a_lds)[i] = 0;
  // park W k-steps 2..3 into LDS: w_lds[ksl*4096 + nt*64 + lane]
  for (int i = tid; i < PKL * 64 * 64; i += 512) {
    int ksl = i >> 12;
    int nt  = (i >> 6) & 63;
    int ln  = i & 63;
    w_lds[i] = wv[(nt * NKS + PKR + ksl) * 64 + ln];
  }

  // per-lane constants: wave owns hidden units [wave*32, wave*32+32)
  // local ntile ln = gate*2 + s  ->  global ntile = gate*16 + wave*2 + s
  float bias_v[8];
  int wb[8], wlo[8];
  #pragma unroll
  for (int ln = 0; ln < 8; ++ln) {
    int g = ln >> 1, s = ln & 1;
    int ntg = g * 16 + wave * 2 + s;
    wb[ln]  = ntg * NKS * 64;
    wlo[ln] = ntg * 64 + lane;
    bias_v[ln] = bias[ntg * 16 + l15];
  }
  float dw_v[2];
  dw_v[0] = dw[wave * 32 + l15];
  dw_v[1] = dw[wave * 32 + 16 + l15];
  const float dbv = db[0];

  // park W k-steps 0..1 in registers (persistent across all timesteps)
  v8s wreg0[8], wreg1[8];
  #pragma unroll
  for (int ln = 0; ln < 8; ++ln) {
    wreg0[ln] = wv[wb[ln] + lane];
    wreg1[ln] = wv[wb[ln] + 64 + lane];
  }

  float cst[2][2][4];           // c state: [mt][s][r]
  #pragma unroll
  for (int mt = 0; mt < 2; ++mt)
    #pragma unroll
    for (int s = 0; s < 2; ++s)
      #pragma unroll
      for (int r = 0; r < 4; ++r) cst[mt][s][r] = 0.f;

  #define REFILL(BUF, rks)                                                    \
    do {                                                                      \
      _Pragma("unroll")                                                       \
      for (int ln = 0; ln < 8; ++ln)                                          \
        BUF[ln] = wv[wb[ln] + (rks) * 64 + lane];                             \
    } while (0)

  // stream double-buffer prologue: ks 4, 5 in flight before first GEMM
  v8s bs0[8], bs1[8];
  REFILL(bs0, SK0);
  REFILL(bs1, SK0 + 1);

  // x prefetch for t=0 (waves 0-3)
  const int ms_x  = tid >> 3;          // valid for tid < 256
  const int kq8_x = tid & 7;
  const int ms_y  = (tid - 256) >> 3;  // valid for tid >= 256
  const int jj    = tid & 7;
  float4 xpa, xpb;
  if (tid < 256) {
    const float* xp = x + ((size_t)((b0 + ms_x) * 64)) * 64 + kq8_x * 8;
    xpa = ((const float4*)xp)[0];
    xpb = ((const float4*)xp)[1];
  }

  __syncthreads();   // full barrier once: a_lds zero + w_lds park visible

  #pragma unroll 1
  for (int t = 0; t < 64; ++t) {
    // ---- P12: merged read+write phase ----
    // yp shift hazard is intra-wave only (each batch row's 8 threads are in one
    // wave; LDS unit services a wave's reads before its later writes), and
    // x-rows / h-rows / yp-rows are disjoint regions -> no barrier needed
    // between the reads and writes.
    if (tid < 256) {                       // waves 0-3: write prefetched x_t
      uint4 w4;
      w4.x = bf16u(xpa.x) | (bf16u(xpa.y) << 16);
      w4.y = bf16u(xpa.z) | (bf16u(xpa.w) << 16);
      w4.z = bf16u(xpb.x) | (bf16u(xpb.y) << 16);
      w4.w = bf16u(xpb.z) | (bf16u(xpb.w) << 16);
      *(uint4*)(a_lds + a_addr(ms_x, kq8_x * 8)) = w4;
    } else {                               // waves 4-7: yp shift / init
      if (t == 0) {
        unsigned short q0 = (unsigned short)bf16u(y0[(b0 + ms_y) * 16 + 2 * jj]);
        unsigned short q1 = (unsigned short)bf16u(y0[(b0 + ms_y) * 16 + 2 * jj + 1]);
        *(unsigned short*)(a_lds + a_addr(ms_y, 64 + 2 * jj))     = q0;
        *(unsigned short*)(a_lds + a_addr(ms_y, 64 + 2 * jj + 1)) = q1;
      } else {
        unsigned short q0 = *(const unsigned short*)(a_lds + a_addr(ms_y, 64 + 2 * jj));
        unsigned short q1 = *(const unsigned short*)(a_lds + a_addr(ms_y, 64 + 2 * jj + 1));
        float pin = predf[ms_y];
        __builtin_amdgcn_sched_barrier(0);   // keep reads before shifted writes
        if (jj < 7) {
          *(unsigned short*)(a_lds + a_addr(ms_y, 64 + 2 * jj + 1)) = q0;
          *(unsigned short*)(a_lds + a_addr(ms_y, 64 + 2 * jj + 2)) = q1;
        } else {
          *(unsigned short*)(a_lds + a_addr(ms_y, 79)) = q0;   // j=14 -> 15
        }
        if (jj == 0)
          *(unsigned short*)(a_lds + a_addr(ms_y, 64)) = (unsigned short)bf16u(pin);
      }
    }
    bar_lds();   // A tile ready for GEMM

    // x_{t+1} prefetch: issued here, consumed next iteration (rides across
    // the lgkm-only barriers).
    if (t < 63 && tid < 256) {
      const float* xp = x + ((size_t)((b0 + ms_x) * 64 + (t + 1))) * 64 + kq8_x * 8;
      xpa = ((const float4*)xp)[0];
      xpb = ((const float4*)xp)[1];
    }

    // ---- P3: GEMM  z[32,1024] += inp[32,352] @ W[352,1024] ----
    v4f acc[2][8];
    #pragma unroll
    for (int mt = 0; mt < 2; ++mt)
      #pragma unroll
      for (int ln = 0; ln < 8; ++ln) acc[mt][ln] = v4f{0.f, 0.f, 0.f, 0.f};

    // LDS-parked weight fragments, issued up front (covered by reg-parked blocks)
    v8s wla[8], wlb[8];
    #pragma unroll
    for (int ln = 0; ln < 8; ++ln) wla[ln] = w_lds[wlo[ln]];
    #pragma unroll
    for (int ln = 0; ln < 8; ++ln) wlb[ln] = w_lds[4096 + wlo[ln]];
    v8s af0 = *(const v8s*)(a_lds + (lane << 4));
    v8s af1 = *(const v8s*)(a_lds + (NKS << 10) + (lane << 4));

    // A-fragment prefetch + 16 MFMA on weight fragments W8, for tile ks.
    #define MFMA_BLK(ksi, W8)                                                   \
      do {                                                                      \
        v8s c0 = af0, c1 = af1;                                                 \
        if ((ksi) < NKS - 1) {                                                  \
          af0 = *(const v8s*)(a_lds + (((ksi) + 1) << 10) + (lane << 4));       \
          af1 = *(const v8s*)(a_lds + ((NKS + (ksi) + 1) << 10) + (lane << 4)); \
        }                                                                       \
        _Pragma("unroll")                                                       \
        for (int ln = 0; ln < 8; ++ln) {                                        \
          acc[0][ln] = __builtin_amdgcn_mfma_f32_16x16x32_bf16(c0, W8[ln], acc[0][ln], 0, 0, 0); \
          acc[1][ln] = __builtin_amdgcn_mfma_f32_16x16x32_bf16(c1, W8[ln], acc[1][ln], 0, 0, 0); \
        }                                                                       \
      } while (0)

    MFMA_BLK(0, wreg0);
    MFMA_BLK(1, wreg1);
    MFMA_BLK(2, wla);
    MFMA_BLK(3, wlb);
    // streamed ks 4..10: consume-then-refill at distance 2; the last two
    // refills are NEXT STEP's ks4/ks5 (cross-step prefetch, huge cover).
    MFMA_BLK(4, bs0);   REFILL(bs0, 6);
    MFMA_BLK(5, bs1);   REFILL(bs1, 7);
    MFMA_BLK(6, bs0);   REFILL(bs0, 8);
    MFMA_BLK(7, bs1);   REFILL(bs1, 9);
    MFMA_BLK(8, bs0);   REFILL(bs0, 10);
    MFMA_BLK(9, bs1);   REFILL(bs1, SK0 + 1);   // next-step ks5
    MFMA_BLK(10, bs0);  REFILL(bs0, SK0);       // next-step ks4

    #undef MFMA_BLK

    bar_lds();   // all A reads done before h-row writes

    // ---- P4: gates, c/h update, h->A, pred partials ----
    float padd[2][4];
    #pragma unroll
    for (int mt = 0; mt < 2; ++mt)
      #pragma unroll
      for (int r = 0; r < 4; ++r) padd[mt][r] = 0.f;

    #pragma unroll
    for (int mt = 0; mt < 2; ++mt) {
      #pragma unroll
      for (int s = 0; s < 2; ++s) {
        const int kk = 80 + wave * 32 + s * 16 + l15;    // h row in A
        #pragma unroll
        for (int r = 0; r < 4; ++r) {
          float zi = acc[mt][0 + s][r] + bias_v[0 + s];
          float zf = acc[mt][2 + s][r] + bias_v[2 + s];
          float zg = acc[mt][4 + s][r] + bias_v[4 + s];
          float zo = acc[mt][6 + s][r] + bias_v[6 + s];
          float is = sigm(zi), fs = sigm(zf), gs = tanh_(zg), os = sigm(zo);
          float cn = fs * cst[mt][s][r] + is * gs;
          cst[mt][s][r] = cn;
          float hh = os * tanh_(cn);
          int m = mt * 16 + quad * 4 + r;
          *(unsigned short*)(a_lds + a_addr(m, kk)) = (unsigned short)bf16u(hh);
          padd[mt][r] += hh * dw_v[s];
        }
      }
    }
    // reduce pred partial over the 16-lane column group
    #pragma unroll
    for (int mt = 0; mt < 2; ++mt) {
      #pragma unroll
      for (int r = 0; r < 4; ++r) {
        float p = padd[mt][r];
        p += __shfl_xor(p, 1);
        p += __shfl_xor(p, 2);
        p += __shfl_xor(p, 4);
        p += __shfl_xor(p, 8);
        if (l15 == 0) predbuf[mt * 16 + quad * 4 + r][wave] = p;
      }
    }
    bar_lds();
    // ---- P5: finalize pred, write output ----
    if (tid < 32) {
      float p = dbv;
      #pragma unroll
      for (int w = 0; w < 8; ++w) p += predbuf[tid][w];
      out[(size_t)(b0 + tid) * 64 + t] = p;
      predf[tid] = p;
    }
    bar_lds();
  }
  #undef REFILL
}

extern "C" void kernel_launch(void* const* d_in, const int* in_sizes, int n_in,
                              void* d_out, int out_size, void* d_ws, size_t ws_size,
                              hipStream_t stream) {
  const float* x    = (const float*)d_in[0];
  const float* y0   = (const float*)d_in[1];
  const float* ker  = (const float*)d_in[2];
  const float* rec  = (const float*)d_in[3];
  const float* bias = (const float*)d_in[4];
  const float* dw   = (const float*)d_in[5];
  const float* db   = (const float*)d_in[6];

  // swizzled weights: 64 ntiles * 11 ksteps * 64 lanes * 16B = 720896 B in d_ws
  prep_w<<<dim3(176), dim3(256), 0, stream>>>(ker, rec, (uint4*)d_ws);
  lstm_main<<<dim3(256), dim3(512), 0, stream>>>(x, y0, bias, dw, db,
                                                 (const v8s*)d_ws, (float*)d_out);
}